// Round 1
// baseline (215.138 us; speedup 1.0000x reference)
//
#include <hip/hip_runtime.h>
#include <math.h>
#include <stdint.h>

// TreeLSTM, 32 complete binary trees depth 10, heap order, d=128.
// R7: (1) fix launch_bounds unit bug — (512,2) was 1 block/CU, now (512,4)
//     = 2 blocks/CU on gemm_leaf (it was latency-bound: 19% occ, 23% HBM).
//     (2) wx layout gate-interleaved [node][col][4] -> consumers do one 8B
//     load per parent instead of 4 scalar 2B loads; gemm epilogue writes one
//     contiguous 32B chunk per lane. (3) big_level_k templated on NCT
//     (parents/block = 8*NCT): dep9/8/7 all run 512 blocks (was 512/256/128),
//     small variants get 4 waves/EU.

#define NTREES 32
#define MTREE 2047
#define NNODES (NTREES * MTREE)   // 65504

typedef __attribute__((ext_vector_type(8))) short bf16x8;
typedef __attribute__((ext_vector_type(4))) float f32x4;

__device__ __forceinline__ float sigmoidf_(float x) {
    return 1.0f / (1.0f + __expf(-x));
}
__device__ __forceinline__ float tanhf_(float x) {
    x = fminf(fmaxf(x, -10.0f), 10.0f);
    float e = __expf(2.0f * x);
    return (e - 1.0f) / (e + 1.0f);
}
__device__ __forceinline__ float bf2f(uint16_t b) {
    union { uint32_t u; float f; } v; v.u = ((uint32_t)b) << 16; return v.f;
}
__device__ __forceinline__ uint16_t f2bf(float f) {
    union { float f; uint32_t u; } v; v.f = f;
    uint32_t r = v.u + 0x7FFF + ((v.u >> 16) & 1);   // RNE
    return (uint16_t)(r >> 16);
}
__device__ __forceinline__ uint4 pack_bf8(float4 a, float4 b) {
    uint4 r;
    r.x = (uint32_t)f2bf(a.x) | ((uint32_t)f2bf(a.y) << 16);
    r.y = (uint32_t)f2bf(a.z) | ((uint32_t)f2bf(a.w) << 16);
    r.z = (uint32_t)f2bf(b.x) | ((uint32_t)f2bf(b.y) << 16);
    r.w = (uint32_t)f2bf(b.z) | ((uint32_t)f2bf(b.w) << 16);
    return r;
}

// Swizzled LDS layout: bf16 rows of 128 (16 chunks of 16B), XOR by row&7.
#define SWZ(row, chunk) ((row) * 128 + (((chunk) ^ ((row) & 7)) * 8))

// ---------------------------------------------------------------------------
__global__ __launch_bounds__(128) void prep_k(const float* __restrict__ Wiou,
                                              const float* __restrict__ Wf,
                                              const float* __restrict__ Uiou,
                                              const float* __restrict__ Uf,
                                              const float* __restrict__ biou,
                                              const float* __restrict__ bf,
                                              uint16_t* __restrict__ WT,
                                              uint16_t* __restrict__ UT,
                                              float* __restrict__ biasS) {
    int n = blockIdx.x, k = threadIdx.x;
    if (n < 512) {
        WT[n * 128 + k] = f2bf(n < 384 ? Wiou[k * 384 + n] : Wf[k * 128 + (n - 384)]);
    } else if (n < 1024) {
        int m = n - 512;
        UT[m * 128 + k] = f2bf(m < 384 ? Uiou[k * 384 + m] : Uf[k * 128 + (m - 384)]);
    } else {
#pragma unroll
        for (int r = 0; r < 4; ++r) {
            int j = r * 128 + k;
            biasS[j] = j < 384 ? biou[j] : bf[j - 384];
        }
    }
}

// ---------------------------------------------------------------------------
// Fused GEMM + leaf epilogue.
// wx layout (NEW): wx[v*512 + col*4 + gate], gate = {0:i,1:o,2:u,3:f}.
__global__ __launch_bounds__(512, 4) void gemm_leaf_k(const float* __restrict__ F,
                                                      const uint16_t* __restrict__ WT,
                                                      const float* __restrict__ biasS,
                                                      uint16_t* __restrict__ wx,
                                                      float* __restrict__ h,
                                                      float* __restrict__ c) {
    __shared__ uint16_t Fs[64 * 128];
    const int tid = threadIdx.x;
    const int w = tid >> 6, lane = tid & 63, q = lane >> 4, l15 = lane & 15;
    const int n0 = blockIdx.x * 64;

#pragma unroll
    for (int r = 0; r < 2; ++r) {
        int ci = r * 512 + tid;
        int row = ci >> 4, cx = ci & 15;
        int v = n0 + row; v = v < NNODES ? v : NNODES - 1;
        const float* src = F + (size_t)v * 128 + cx * 8;
        float4 f0 = *(const float4*)src;
        float4 f1 = *(const float4*)(src + 4);
        *(uint4*)&Fs[SWZ(row, cx)] = pack_bf8(f0, f1);
    }
    bf16x8 aW[4][4];
    float4 bias4[4];
#pragma unroll
    for (int s = 0; s < 4; ++s) {
        int row = (w + s * 8) * 16 + l15;
#pragma unroll
        for (int kc = 0; kc < 4; ++kc)
            aW[s][kc] = *(const bf16x8*)(WT + (size_t)row * 128 + kc * 32 + q * 8);
        bias4[s] = *(const float4*)(biasS + (w + s * 8) * 16 + q * 4);
    }
    __syncthreads();

#pragma unroll
    for (int nt = 0; nt < 4; ++nt) {
        bf16x8 b[4];
#pragma unroll
        for (int kc = 0; kc < 4; ++kc)
            b[kc] = *(const bf16x8*)&Fs[SWZ(nt * 16 + l15, kc * 4 + q)];
        f32x4 acc[4] = {};
#pragma unroll
        for (int s = 0; s < 4; ++s)
#pragma unroll
            for (int kc = 0; kc < 4; ++kc)
                acc[s] = __builtin_amdgcn_mfma_f32_16x16x32_bf16(aW[s][kc], b[kc], acc[s], 0, 0, 0);

        int node = n0 + nt * 16 + l15;
        bool nvalid = node < NNODES;
        int v = nvalid ? node : NNODES - 1;
        int tree = v / 2047;
        int j = v - tree * 2047;
        bool leaf = j >= 1023;
        float pi[4], po[4], pu[4], pf[4];
#pragma unroll
        for (int r = 0; r < 4; ++r) {
            pi[r] = acc[0][r] + bias4[0][r];
            po[r] = acc[1][r] + bias4[1][r];
            pu[r] = acc[2][r] + bias4[2][r];
            pf[r] = acc[3][r] + bias4[3][r];
        }
        int colb = w * 16 + q * 4;
        if (nvalid && leaf) {
            float cv[4], hv[4];
#pragma unroll
            for (int r = 0; r < 4; ++r) {
                float iv = sigmoidf_(pi[r]);
                float ov = sigmoidf_(po[r]);
                float uv = tanhf_(pu[r]);
                float cn = iv * uv;
                cv[r] = cn;
                hv[r] = ov * tanhf_(cn);
            }
            *(float4*)&c[(size_t)v * 128 + colb] = *(float4*)cv;
            *(float4*)&h[(size_t)v * 128 + colb] = *(float4*)hv;
        }
        if (nvalid && !leaf) {
            // gate-interleaved: 16 consecutive uint16 = 32B contiguous
            uint4 w0, w1;
            w0.x = (uint32_t)f2bf(pi[0]) | ((uint32_t)f2bf(po[0]) << 16);
            w0.y = (uint32_t)f2bf(pu[0]) | ((uint32_t)f2bf(pf[0]) << 16);
            w0.z = (uint32_t)f2bf(pi[1]) | ((uint32_t)f2bf(po[1]) << 16);
            w0.w = (uint32_t)f2bf(pu[1]) | ((uint32_t)f2bf(pf[1]) << 16);
            w1.x = (uint32_t)f2bf(pi[2]) | ((uint32_t)f2bf(po[2]) << 16);
            w1.y = (uint32_t)f2bf(pu[2]) | ((uint32_t)f2bf(pf[2]) << 16);
            w1.z = (uint32_t)f2bf(pi[3]) | ((uint32_t)f2bf(po[3]) << 16);
            w1.w = (uint32_t)f2bf(pu[3]) | ((uint32_t)f2bf(pf[3]) << 16);
            uint16_t* wr = wx + (size_t)v * 512 + colb * 4;
            *(uint4*)(wr) = w0;
            *(uint4*)(wr + 8) = w1;
        }
    }
}

// ---------------------------------------------------------------------------
__device__ __forceinline__ void load_bU(const uint16_t* __restrict__ UT, bf16x8 bU[4][4]) {
    const int tid = threadIdx.x;
    const int w = tid >> 6, lane = tid & 63, q = lane >> 4, l15 = lane & 15;
#pragma unroll
    for (int s = 0; s < 4; ++s) {
        int row = (w + s * 8) * 16 + l15;   // s: 0=i,1=o,2=u,3=f column blocks
#pragma unroll
        for (int kc = 0; kc < 4; ++kc)
            bU[s][kc] = *(const bf16x8*)(UT + (size_t)row * 128 + kc * 32 + q * 8);
    }
}

// ---------------------------------------------------------------------------
// Levels dep 9/8/7: 8*NCT parents (16*NCT children) per block, grid-parallel.
// Per-child matvec for all 4 gates; parent = in-lane f32 pair-sum. One barrier.
template<int NCT>
__global__ __launch_bounds__(512, NCT == 4 ? 2 : 4) void big_level_k(const uint16_t* __restrict__ wx,
                                                                     const uint16_t* __restrict__ UT,
                                                                     float* __restrict__ h,
                                                                     float* __restrict__ c,
                                                                     int dep) {
    __shared__ uint16_t Hc[16 * NCT * 128];
    bf16x8 bU[4][4];
    load_bU(UT, bU);
    const int tid = threadIdx.x;
    const int w = tid >> 6, lane = tid & 63, q = lane >> 4, l15 = lane & 15;
    const int colf = w * 16 + l15;
    int idx0 = blockIdx.x * (8 * NCT);
    int tree = idx0 >> dep;
    int pos0 = idx0 - (tree << dep);
    int np = 1 << dep;
    int vp = tree * MTREE + (np - 1) + pos0;
    int vc = tree * MTREE + (2 * np - 1) + 2 * pos0;

    // scattered wx + child-c loads issued first (latency hides under staging+MFMA)
    float wxg[NCT][2][4];
#pragma unroll
    for (int ct = 0; ct < NCT; ++ct)
#pragma unroll
        for (int j = 0; j < 2; ++j) {
            int pl = ct * 8 + q * 2 + j;
            ushort4 g = *(const ushort4*)(wx + (size_t)(vp + pl) * 512 + colf * 4);
            wxg[ct][j][0] = bf2f(g.x);
            wxg[ct][j][1] = bf2f(g.y);
            wxg[ct][j][2] = bf2f(g.z);
            wxg[ct][j][3] = bf2f(g.w);
        }
    float cch[NCT][4];
#pragma unroll
    for (int ct = 0; ct < NCT; ++ct)
#pragma unroll
        for (int r = 0; r < 4; ++r) {
            int cl = ct * 16 + q * 4 + r;
            cch[ct][r] = c[(size_t)(vc + cl) * 128 + colf];
        }

    // stage 16*NCT child-h rows f32 -> bf16 swizzled
#pragma unroll
    for (int t = 0; t < (16 * NCT * 16 + 511) / 512; ++t) {
        int ci = t * 512 + tid;
        if (ci < 16 * NCT * 16) {
            int row = ci >> 4, cx = ci & 15;
            const float* src = h + (size_t)(vc + row) * 128 + cx * 8;
            float4 f0 = *(const float4*)src;
            float4 f1 = *(const float4*)(src + 4);
            *(uint4*)&Hc[SWZ(row, cx)] = pack_bf8(f0, f1);
        }
    }
    __syncthreads();

    // per-child matvec: NCT child-tiles x 4 gates x 4 k-chunks
    f32x4 acc[NCT][4] = {};
#pragma unroll
    for (int ct = 0; ct < NCT; ++ct) {
        bf16x8 a[4];
#pragma unroll
        for (int kc = 0; kc < 4; ++kc)
            a[kc] = *(const bf16x8*)&Hc[SWZ(ct * 16 + l15, kc * 4 + q)];
#pragma unroll
        for (int s = 0; s < 4; ++s)
#pragma unroll
            for (int kc = 0; kc < 4; ++kc)
                acc[ct][s] = __builtin_amdgcn_mfma_f32_16x16x32_bf16(a[kc], bU[s][kc], acc[ct][s], 0, 0, 0);
    }

    // lane-local epilogue: f per child, pair-sum everything per parent
#pragma unroll
    for (int ct = 0; ct < NCT; ++ct) {
        float fc[4];
#pragma unroll
        for (int r = 0; r < 4; ++r)
            fc[r] = sigmoidf_(acc[ct][3][r] + wxg[ct][r >> 1][3]) * cch[ct][r];
#pragma unroll
        for (int j = 0; j < 2; ++j) {
            int pl = ct * 8 + q * 2 + j;
            float ip = acc[ct][0][2 * j] + acc[ct][0][2 * j + 1] + wxg[ct][j][0];
            float op = acc[ct][1][2 * j] + acc[ct][1][2 * j + 1] + wxg[ct][j][1];
            float up = acc[ct][2][2 * j] + acc[ct][2][2 * j + 1] + wxg[ct][j][2];
            float cn = sigmoidf_(ip) * tanhf_(up) + fc[2 * j] + fc[2 * j + 1];
            float hv = sigmoidf_(op) * tanhf_(cn);
            c[(size_t)(vp + pl) * 128 + colf] = cn;
            h[(size_t)(vp + pl) * 128 + colf] = hv;
        }
    }
}

// ---------------------------------------------------------------------------
// Tail: dep 6..0, one block per tree, 8 groups, one barrier per group.
// h in LDS (Hbuf rows 0..127 / 128..191 alternating), c in LDS CS halves.
__global__ __launch_bounds__(512, 1) void tail_k(const uint16_t* __restrict__ wx,
                                                 const uint16_t* __restrict__ UT,
                                                 const float* __restrict__ cglob,
                                                 float* __restrict__ h) {
    __shared__ uint16_t Hbuf[192 * 128];   // 48 KB
    __shared__ float CS[128 * 132];        // 66 KB, stride 132 (2-way-free banks)
    bf16x8 bU[4][4];
    load_bU(UT, bU);
    const int tree = blockIdx.x;
    const int tid = threadIdx.x;
    const int w = tid >> 6, lane = tid & 63, q = lane >> 4, l15 = lane & 15;
    const int colf = w * 16 + l15;
    const int vbase = tree * MTREE;

    // stage dep-7 h (tree-local nodes 127..254) into Hbuf rows 0..127
#pragma unroll
    for (int t = 0; t < 4; ++t) {
        int ci = t * 512 + tid;
        int row = ci >> 4, cx = ci & 15;
        const float* src = h + (size_t)(vbase + 127 + row) * 128 + cx * 8;
        float4 f0 = *(const float4*)src;
        float4 f1 = *(const float4*)(src + 4);
        *(uint4*)&Hbuf[SWZ(row, cx)] = pack_bf8(f0, f1);
    }

#pragma unroll 1
    for (int gi = 0; gi < 8; ++gi) {
        const int dep = gi < 2 ? 6 : 7 - gi;
        const int np = 1 << dep;
        const int pos0 = (gi == 1) ? 32 : 0;
        const int P = gi < 3 ? 32 : np;
        const int pL = dep & 1;              // 0 for dep 6,4,2,0
        const int childBase = pL ? 128 : 0;
        const int parBase = pL ? 0 : 128;
        const int csRead = pL ? 0 : 64;
        const int csWrite = pL ? 64 : 0;
        const int vp = vbase + (np - 1) + pos0;
        __syncthreads();

        // wx for this lane's 8 parents (4 gates each) — one 8B load per parent
        float wxg[4][2][4];
#pragma unroll
        for (int ct = 0; ct < 4; ++ct)
#pragma unroll
            for (int j = 0; j < 2; ++j) {
                int pl = ct * 8 + q * 2 + j;
                ushort4 g = *(const ushort4*)(wx + (size_t)(vp + pl) * 512 + colf * 4);
                wxg[ct][j][0] = bf2f(g.x);
                wxg[ct][j][1] = bf2f(g.y);
                wxg[ct][j][2] = bf2f(g.z);
                wxg[ct][j][3] = bf2f(g.w);
            }
        // child c: global (dep6) or CS (below)
        float cch[4][4];
        if (gi < 2) {
#pragma unroll
            for (int ct = 0; ct < 4; ++ct)
#pragma unroll
                for (int r = 0; r < 4; ++r) {
                    int cl = 2 * pos0 + ct * 16 + q * 4 + r;
                    cch[ct][r] = cglob[(size_t)(vbase + 127 + cl) * 128 + colf];
                }
        } else {
#pragma unroll
            for (int ct = 0; ct < 4; ++ct)
#pragma unroll
                for (int r = 0; r < 4; ++r) {
                    int cl = ct * 16 + q * 4 + r;
                    cch[ct][r] = CS[(csRead + cl) * 132 + colf];
                }
        }

        // per-child matvec
        f32x4 acc[4][4] = {};
#pragma unroll
        for (int ct = 0; ct < 4; ++ct) {
            bf16x8 a[4];
#pragma unroll
            for (int kc = 0; kc < 4; ++kc) {
                int row = childBase + 2 * pos0 + ct * 16 + l15;
                a[kc] = *(const bf16x8*)&Hbuf[SWZ(row, kc * 4 + q)];
            }
#pragma unroll
            for (int s = 0; s < 4; ++s)
#pragma unroll
                for (int kc = 0; kc < 4; ++kc)
                    acc[ct][s] = __builtin_amdgcn_mfma_f32_16x16x32_bf16(a[kc], bU[s][kc], acc[ct][s], 0, 0, 0);
        }

        // lane-local epilogue
#pragma unroll
        for (int ct = 0; ct < 4; ++ct) {
            float fc[4];
#pragma unroll
            for (int r = 0; r < 4; ++r)
                fc[r] = sigmoidf_(acc[ct][3][r] + wxg[ct][r >> 1][3]) * cch[ct][r];
#pragma unroll
            for (int j = 0; j < 2; ++j) {
                int pl = ct * 8 + q * 2 + j;
                float ip = acc[ct][0][2 * j] + acc[ct][0][2 * j + 1] + wxg[ct][j][0];
                float op = acc[ct][1][2 * j] + acc[ct][1][2 * j + 1] + wxg[ct][j][1];
                float up = acc[ct][2][2 * j] + acc[ct][2][2 * j + 1] + wxg[ct][j][2];
                float cn = sigmoidf_(ip) * tanhf_(up) + fc[2 * j] + fc[2 * j + 1];
                float hv = sigmoidf_(op) * tanhf_(cn);
                if (pl < P) {
                    h[(size_t)(vp + pl) * 128 + colf] = hv;
                    int row = parBase + pos0 + pl;       // next level's child row
                    Hbuf[row * 128 + (((colf >> 3) ^ (row & 7)) * 8) + (colf & 7)] = f2bf(hv);
                    CS[(csWrite + pos0 + pl) * 132 + colf] = cn;
                }
            }
        }
    }
}

// ---------------------------------------------------------------------------
extern "C" void kernel_launch(void* const* d_in, const int* in_sizes, int n_in,
                              void* d_out, int out_size, void* d_ws, size_t ws_size,
                              hipStream_t stream) {
    const float* features = (const float*)d_in[0];
    const float* W_iou    = (const float*)d_in[1];
    const float* b_iou    = (const float*)d_in[2];
    const float* U_iou    = (const float*)d_in[3];
    const float* W_f      = (const float*)d_in[4];
    const float* b_f      = (const float*)d_in[5];
    const float* U_f      = (const float*)d_in[6];
    float* h = (float*)d_out;

    char* wp = (char*)d_ws;
    uint16_t* wx    = (uint16_t*)wp; wp += (size_t)NNODES * 512 * 2;
    float*    c     = (float*)wp;    wp += (size_t)NNODES * 128 * 4;
    uint16_t* WT    = (uint16_t*)wp; wp += 512 * 128 * 2;
    uint16_t* UT    = (uint16_t*)wp; wp += 512 * 128 * 2;
    float*    biasS = (float*)wp;    wp += 512 * 4;

    hipLaunchKernelGGL(prep_k, dim3(1025), dim3(128), 0, stream,
                       W_iou, W_f, U_iou, U_f, b_iou, b_f, WT, UT, biasS);
    hipLaunchKernelGGL(gemm_leaf_k, dim3(1024), dim3(512), 0, stream,
                       features, WT, biasS, wx, h, c);
    hipLaunchKernelGGL((big_level_k<4>), dim3(512), dim3(512), 0, stream, wx, UT, h, c, 9);
    hipLaunchKernelGGL((big_level_k<2>), dim3(512), dim3(512), 0, stream, wx, UT, h, c, 8);
    hipLaunchKernelGGL((big_level_k<1>), dim3(512), dim3(512), 0, stream, wx, UT, h, c, 7);
    hipLaunchKernelGGL(tail_k, dim3(32), dim3(512), 0, stream, wx, UT, c, h);
}